// Round 9
// baseline (291.112 us; speedup 1.0000x reference)
//
#include <hip/hip_runtime.h>
#include <hip/hip_fp16.h>

#define N_NODES 50000
#define N_EDGES 800000
#define IN_F 128
#define HID 96
#define NCLS 21
#define NBUCK 196        // coarse bucket = tgt>>8  (49999>>8 = 195)
#define BCAP  4608       // per-bucket capacity: mean 4082, +8 sigma
#define CPAD  16         // cursor stride in ints -> one 64B line per counter

// ---------------- pass 1: bin edges by tgt>>8 (dense-in-time writes) ----------------
__global__ __launch_bounds__(1024) void k_bin(
    const int* __restrict__ src, const int* __restrict__ tgt,
    int* __restrict__ cursor, int* __restrict__ packed) {
  __shared__ int lhist[NBUCK];
  __shared__ int gbase[NBUCK];
  int tid = threadIdx.x;
  if (tid < NBUCK) lhist[tid] = 0;
  __syncthreads();
  int me = blockIdx.x * 4096 + tid * 4;
  int4 t4, s4;
  int b0 = 0, b1 = 0, b2 = 0, b3 = 0;
  bool valid = me < N_EDGES;
  if (valid) {
    t4 = *reinterpret_cast<const int4*>(tgt + me);
    s4 = *reinterpret_cast<const int4*>(src + me);
    b0 = t4.x >> 8; b1 = t4.y >> 8; b2 = t4.z >> 8; b3 = t4.w >> 8;
    atomicAdd(&lhist[b0], 1); atomicAdd(&lhist[b1], 1);
    atomicAdd(&lhist[b2], 1); atomicAdd(&lhist[b3], 1);
  }
  __syncthreads();
  if (tid < NBUCK) {
    int c = lhist[tid];
    gbase[tid] = c ? atomicAdd(&cursor[tid * CPAD], c) : 0;
    lhist[tid] = 0;
  }
  __syncthreads();
  if (valid) {
    int r, pos;
    r = atomicAdd(&lhist[b0], 1);
    pos = gbase[b0] + r;
    if (pos < BCAP) packed[b0 * BCAP + pos] = (s4.x << 8) | (t4.x & 255);
    r = atomicAdd(&lhist[b1], 1);
    pos = gbase[b1] + r;
    if (pos < BCAP) packed[b1 * BCAP + pos] = (s4.y << 8) | (t4.y & 255);
    r = atomicAdd(&lhist[b2], 1);
    pos = gbase[b2] + r;
    if (pos < BCAP) packed[b2 * BCAP + pos] = (s4.z << 8) | (t4.z & 255);
    r = atomicAdd(&lhist[b3], 1);
    pos = gbase[b3] + r;
    if (pos < BCAP) packed[b3 * BCAP + pos] = (s4.w << 8) | (t4.w & 255);
  }
}

// ---------------- pass 2: per-bucket LDS counting sort -> CSR + deg + dinv ----------------
__global__ __launch_bounds__(256) void k_build(
    const int* __restrict__ cursor, const int* __restrict__ packed,
    int* __restrict__ adj, int* __restrict__ degarr,
    int* __restrict__ rowptr, float* __restrict__ dinv) {
  __shared__ int ncnt[256];
  __shared__ int noff[256];
  __shared__ int nrank[256];
  __shared__ int ws[4];
  int b = blockIdx.x;
  int tid = threadIdx.x;
  int cntb = cursor[b * CPAD];
  if (cntb > BCAP) cntb = BCAP;
  ncnt[tid] = 0;
  nrank[tid] = 0;
  __syncthreads();
  const int* pk = packed + b * BCAP;
  for (int i = tid; i < cntb; i += 256) atomicAdd(&ncnt[pk[i] & 255], 1);
  __syncthreads();
  // exclusive scan of ncnt -> noff
  {
    int lane = tid & 63, wid = tid >> 6;
    int v = ncnt[tid];
    int x = v;
#pragma unroll
    for (int off = 1; off < 64; off <<= 1) {
      int y = __shfl_up(x, off);
      if (lane >= off) x += y;
    }
    if (lane == 63) ws[wid] = x;
    __syncthreads();
    if (tid == 0) {
      int t0 = ws[0], t1 = ws[1], t2 = ws[2];
      ws[3] = t0 + t1 + t2; ws[2] = t0 + t1; ws[1] = t0; ws[0] = 0;
    }
    __syncthreads();
    noff[tid] = ws[wid] + x - v;
  }
  __syncthreads();
  int n = (b << 8) + tid;
  if (n < N_NODES) {
    int d = ncnt[tid];
    degarr[n] = d;
    rowptr[n] = b * BCAP + noff[tid];
    dinv[n] = rsqrtf(1.0f + (float)d);  // +1 self-loop
  }
  __syncthreads();
  for (int i = tid; i < cntb; i += 256) {
    int e = pk[i];
    int low = e & 255;
    int r = atomicAdd(&nrank[low], 1);
    adj[b * BCAP + noff[low] + r] = e >> 8;
  }
}

// ---------------- register-tiled GEMM: g[n][f] = fp16(dinv[n]*(A@W)[n][f]) ----------------
// 128 threads -> 64 nodes x 96 feats; thread: 8x6 register tile
template<int K>
__global__ __launch_bounds__(128) void k_gemm_tile(
    const float* __restrict__ A, const float* __restrict__ W,
    const float* __restrict__ dinv, __half* __restrict__ g) {
  constexpr int BM = 64, KB = 32;
  __shared__ float As[KB][BM + 4];
  __shared__ float Ws[KB][HID];
  int tid = threadIdx.x;       // 0..127
  int tx = tid & 15;           // f0 = tx*6
  int ty = tid >> 4;           // 0..7 -> rows ty*8..ty*8+7
  int f0 = tx * 6;
  int nbase = blockIdx.x * BM;
  float acc[8][6] = {};

  for (int k0 = 0; k0 < K; k0 += KB) {
#pragma unroll
    for (int i = 0; i < 4; i++) {
      int l = tid + i * 128;
      int row = l >> 3;
      int col = (l & 7) * 4;
      int n = nbase + row;
      float4 a4 = make_float4(0.f, 0.f, 0.f, 0.f);
      if (n < N_NODES) a4 = *reinterpret_cast<const float4*>(A + (size_t)n * K + k0 + col);
      As[col + 0][row] = a4.x;
      As[col + 1][row] = a4.y;
      As[col + 2][row] = a4.z;
      As[col + 3][row] = a4.w;
    }
#pragma unroll
    for (int i = 0; i < 6; i++) {
      int l = tid + i * 128;
      int row = l / 24;
      int col = (l % 24) * 4;
      *reinterpret_cast<float4*>(&Ws[row][col]) =
          *reinterpret_cast<const float4*>(W + (size_t)(k0 + row) * HID + col);
    }
    __syncthreads();
#pragma unroll
    for (int k = 0; k < KB; k++) {
      float4 alo = *reinterpret_cast<const float4*>(&As[k][ty * 8]);
      float4 ahi = *reinterpret_cast<const float4*>(&As[k][ty * 8 + 4]);
      float2 w01 = *reinterpret_cast<const float2*>(&Ws[k][f0]);
      float2 w23 = *reinterpret_cast<const float2*>(&Ws[k][f0 + 2]);
      float2 w45 = *reinterpret_cast<const float2*>(&Ws[k][f0 + 4]);
      float av[8] = {alo.x, alo.y, alo.z, alo.w, ahi.x, ahi.y, ahi.z, ahi.w};
      float wv[6] = {w01.x, w01.y, w23.x, w23.y, w45.x, w45.y};
#pragma unroll
      for (int i = 0; i < 8; i++)
#pragma unroll
        for (int j = 0; j < 6; j++) acc[i][j] += av[i] * wv[j];
    }
    __syncthreads();
  }

#pragma unroll
  for (int i = 0; i < 8; i++) {
    int n = nbase + ty * 8 + i;
    if (n >= N_NODES) break;
    float d = dinv[n];
    __half2* gp = reinterpret_cast<__half2*>(g + (size_t)n * HID + f0);
#pragma unroll
    for (int j = 0; j < 3; j++)
      gp[j] = __floats2half2_rn(acc[i][2 * j] * d, acc[i][2 * j + 1] * d);
  }
}

// ---------------- fused aggregate: h = leaky(dinv*(g[n] + sum_in g[src]) + b) ----------------
// 128-thr block = 2 waves, one node per wave (32 waves/CU possible).
// fp16 gather payload: 192 B/row = 2 cache lines (was 3), 9.6 MB array (L2-friendlier).
__global__ __launch_bounds__(128) void k_aggregate(
    const __half* __restrict__ g, const int* __restrict__ degarr,
    const int* __restrict__ rowptr, const int* __restrict__ adj,
    const float* __restrict__ dinv, const float* __restrict__ b,
    float* __restrict__ h) {
  int n = blockIdx.x * 2 + (threadIdx.x >> 6);
  if (n >= N_NODES) return;
  int lane = threadIdx.x & 63;
  bool lo = lane < 32;
  int deg = degarr[n];
  const int* al = adj + rowptr[n];
  int myidx = (lane < deg) ? al[lane] : 0;   // coalesced row load

  const __half* grow = g + (size_t)n * HID;
  float s0 = __half2float(grow[lane]);
  float s1 = lo ? __half2float(grow[64 + lane]) : 0.f;

  int dd = deg > 64 ? 64 : deg;
  int j = 0;
  for (; j + 16 <= dd; j += 16) {
    const __half* p[16];
#pragma unroll
    for (int u = 0; u < 16; u++) p[u] = g + (size_t)__shfl(myidx, j + u) * HID;
    float a[16], c[16];
#pragma unroll
    for (int u = 0; u < 16; u++) a[u] = __half2float(p[u][lane]);
#pragma unroll
    for (int u = 0; u < 16; u++) c[u] = lo ? __half2float(p[u][64 + lane]) : 0.f;
#pragma unroll
    for (int u = 0; u < 16; u++) { s0 += a[u]; s1 += c[u]; }
  }
  if (j + 8 <= dd) {
    const __half* p[8];
#pragma unroll
    for (int u = 0; u < 8; u++) p[u] = g + (size_t)__shfl(myidx, j + u) * HID;
    float a[8], c[8];
#pragma unroll
    for (int u = 0; u < 8; u++) a[u] = __half2float(p[u][lane]);
#pragma unroll
    for (int u = 0; u < 8; u++) c[u] = lo ? __half2float(p[u][64 + lane]) : 0.f;
#pragma unroll
    for (int u = 0; u < 8; u++) { s0 += a[u]; s1 += c[u]; }
    j += 8;
  }
  if (j + 4 <= dd) {
    const __half* p[4];
#pragma unroll
    for (int u = 0; u < 4; u++) p[u] = g + (size_t)__shfl(myidx, j + u) * HID;
    float a[4], c[4];
#pragma unroll
    for (int u = 0; u < 4; u++) a[u] = __half2float(p[u][lane]);
#pragma unroll
    for (int u = 0; u < 4; u++) c[u] = lo ? __half2float(p[u][64 + lane]) : 0.f;
#pragma unroll
    for (int u = 0; u < 4; u++) { s0 += a[u]; s1 += c[u]; }
    j += 4;
  }
  for (; j < dd; j++) {
    const __half* p = g + (size_t)__shfl(myidx, j) * HID;
    s0 += __half2float(p[lane]);
    if (lo) s1 += __half2float(p[64 + lane]);
  }
  for (; j < deg; j++) {  // deg > 64: essentially impossible, but correct
    const __half* p = g + (size_t)al[j] * HID;
    s0 += __half2float(p[lane]);
    if (lo) s1 += __half2float(p[64 + lane]);
  }

  float d = dinv[n];
  float v0 = d * s0 + b[lane];
  h[(size_t)n * HID + lane] = v0 > 0.f ? v0 : 0.01f * v0;
  if (lo) {
    float v1 = d * s1 + b[64 + lane];
    h[(size_t)n * HID + 64 + lane] = v1 > 0.f ? v1 : 0.01f * v1;
  }
}

// ---------------- final linear: out = H @ Wl + bl ----------------
__global__ __launch_bounds__(256) void k_final(
    const float* __restrict__ H, const float* __restrict__ Wl,
    const float* __restrict__ bl, float* __restrict__ out) {
  __shared__ float w[HID * NCLS];
  __shared__ float bs[NCLS];
  int tid = threadIdx.x;
  for (int i = tid; i < HID * NCLS; i += 256) w[i] = Wl[i];
  if (tid < NCLS) bs[tid] = bl[tid];
  __syncthreads();
  int idx = blockIdx.x * 256 + tid;
  if (idx >= N_NODES * NCLS) return;
  int n = idx / NCLS;
  int c = idx - n * NCLS;
  const float* a = H + (size_t)n * HID;
  float s = bs[c];
#pragma unroll
  for (int k = 0; k < HID; k++) s += a[k] * w[k * NCLS + c];
  out[idx] = s;
}

extern "C" void kernel_launch(void* const* d_in, const int* in_sizes, int n_in,
                              void* d_out, int out_size, void* d_ws, size_t ws_size,
                              hipStream_t stream) {
  const float* x  = (const float*)d_in[0];
  const int* ei   = (const int*)d_in[1];
  const int* src  = ei;             // edge_index[0]
  const int* tgt  = ei + N_EDGES;   // edge_index[1]
  const float* W1 = (const float*)d_in[2];
  const float* b1 = (const float*)d_in[3];
  const float* W2 = (const float*)d_in[4];
  const float* b2 = (const float*)d_in[5];
  const float* W3 = (const float*)d_in[6];
  const float* b3 = (const float*)d_in[7];
  const float* Wl = (const float*)d_in[8];
  const float* bl = (const float*)d_in[9];
  float* out = (float*)d_out;

  // workspace layout
  float*  dinv   = (float*)d_ws;                            // N
  __half* gh     = (__half*)(dinv + N_NODES);               // N*96 fp16 (gather payload)
  float*  bufB   = (float*)(gh + (size_t)N_NODES * HID);    // N*96 f32 (h)
  int*    degarr = (int*)(bufB + (size_t)N_NODES * HID);    // N
  int*    rowptr = degarr + N_NODES;                        // N
  int*    cursor = rowptr + N_NODES;                        // NBUCK*CPAD
  int*    packed = cursor + NBUCK * CPAD;                   // NBUCK*BCAP
  int*    adj    = packed + NBUCK * BCAP;                   // NBUCK*BCAP

  // ---- CSR build via 2-level counting sort ----
  hipMemsetAsync(cursor, 0, NBUCK * CPAD * sizeof(int), stream);
  k_bin<<<(N_EDGES + 4095) / 4096, 1024, 0, stream>>>(src, tgt, cursor, packed);
  k_build<<<NBUCK, 256, 0, stream>>>(cursor, packed, adj, degarr, rowptr, dinv);

  const int ggrid = (N_NODES + 63) / 64;
  const int agrid = (N_NODES + 1) / 2;

  // ---- layer 1 ----
  k_gemm_tile<IN_F><<<ggrid, 128, 0, stream>>>(x, W1, dinv, gh);
  k_aggregate<<<agrid, 128, 0, stream>>>(gh, degarr, rowptr, adj, dinv, b1, bufB);
  // ---- layer 2 ----
  k_gemm_tile<HID><<<ggrid, 128, 0, stream>>>(bufB, W2, dinv, gh);
  k_aggregate<<<agrid, 128, 0, stream>>>(gh, degarr, rowptr, adj, dinv, b2, bufB);
  // ---- layer 3 ----
  k_gemm_tile<HID><<<ggrid, 128, 0, stream>>>(bufB, W3, dinv, gh);
  k_aggregate<<<agrid, 128, 0, stream>>>(gh, degarr, rowptr, adj, dinv, b3, bufB);

  // ---- classifier ----
  k_final<<<(N_NODES * NCLS + 255) / 256, 256, 0, stream>>>(bufB, Wl, bl, out);
}

// Round 10
// 212.849 us; speedup vs baseline: 1.3677x; 1.3677x over previous
//
#include <hip/hip_runtime.h>
#include <hip/hip_fp16.h>

#define N_NODES 50000
#define N_EDGES 800000
#define IN_F 128
#define HID 96
#define NCLS 21
#define NBUCK 196        // coarse bucket = tgt>>8  (49999>>8 = 195)
#define BCAP  4608       // per-bucket capacity: mean 4082, +8 sigma
#define CPAD  16         // cursor stride in ints -> one 64B line per counter

// ---------------- pass 1: bin edges by tgt>>8 (dense-in-time writes) ----------------
__global__ __launch_bounds__(1024) void k_bin(
    const int* __restrict__ src, const int* __restrict__ tgt,
    int* __restrict__ cursor, int* __restrict__ packed) {
  __shared__ int lhist[NBUCK];
  __shared__ int gbase[NBUCK];
  int tid = threadIdx.x;
  if (tid < NBUCK) lhist[tid] = 0;
  __syncthreads();
  int me = blockIdx.x * 4096 + tid * 4;
  int4 t4, s4;
  int b0 = 0, b1 = 0, b2 = 0, b3 = 0;
  bool valid = me < N_EDGES;
  if (valid) {
    t4 = *reinterpret_cast<const int4*>(tgt + me);
    s4 = *reinterpret_cast<const int4*>(src + me);
    b0 = t4.x >> 8; b1 = t4.y >> 8; b2 = t4.z >> 8; b3 = t4.w >> 8;
    atomicAdd(&lhist[b0], 1); atomicAdd(&lhist[b1], 1);
    atomicAdd(&lhist[b2], 1); atomicAdd(&lhist[b3], 1);
  }
  __syncthreads();
  if (tid < NBUCK) {
    int c = lhist[tid];
    gbase[tid] = c ? atomicAdd(&cursor[tid * CPAD], c) : 0;
    lhist[tid] = 0;
  }
  __syncthreads();
  if (valid) {
    int r, pos;
    r = atomicAdd(&lhist[b0], 1);
    pos = gbase[b0] + r;
    if (pos < BCAP) packed[b0 * BCAP + pos] = (s4.x << 8) | (t4.x & 255);
    r = atomicAdd(&lhist[b1], 1);
    pos = gbase[b1] + r;
    if (pos < BCAP) packed[b1 * BCAP + pos] = (s4.y << 8) | (t4.y & 255);
    r = atomicAdd(&lhist[b2], 1);
    pos = gbase[b2] + r;
    if (pos < BCAP) packed[b2 * BCAP + pos] = (s4.z << 8) | (t4.z & 255);
    r = atomicAdd(&lhist[b3], 1);
    pos = gbase[b3] + r;
    if (pos < BCAP) packed[b3 * BCAP + pos] = (s4.w << 8) | (t4.w & 255);
  }
}

// ---------------- pass 2: per-bucket LDS counting sort -> CSR + deg + dinv ----------------
__global__ __launch_bounds__(256) void k_build(
    const int* __restrict__ cursor, const int* __restrict__ packed,
    int* __restrict__ adj, int* __restrict__ degarr,
    int* __restrict__ rowptr, float* __restrict__ dinv) {
  __shared__ int ncnt[256];
  __shared__ int noff[256];
  __shared__ int nrank[256];
  __shared__ int ws[4];
  int b = blockIdx.x;
  int tid = threadIdx.x;
  int cntb = cursor[b * CPAD];
  if (cntb > BCAP) cntb = BCAP;
  ncnt[tid] = 0;
  nrank[tid] = 0;
  __syncthreads();
  const int* pk = packed + b * BCAP;
  for (int i = tid; i < cntb; i += 256) atomicAdd(&ncnt[pk[i] & 255], 1);
  __syncthreads();
  // exclusive scan of ncnt -> noff
  {
    int lane = tid & 63, wid = tid >> 6;
    int v = ncnt[tid];
    int x = v;
#pragma unroll
    for (int off = 1; off < 64; off <<= 1) {
      int y = __shfl_up(x, off);
      if (lane >= off) x += y;
    }
    if (lane == 63) ws[wid] = x;
    __syncthreads();
    if (tid == 0) {
      int t0 = ws[0], t1 = ws[1], t2 = ws[2];
      ws[3] = t0 + t1 + t2; ws[2] = t0 + t1; ws[1] = t0; ws[0] = 0;
    }
    __syncthreads();
    noff[tid] = ws[wid] + x - v;
  }
  __syncthreads();
  int n = (b << 8) + tid;
  if (n < N_NODES) {
    int d = ncnt[tid];
    degarr[n] = d;
    rowptr[n] = b * BCAP + noff[tid];
    dinv[n] = rsqrtf(1.0f + (float)d);  // +1 self-loop
  }
  __syncthreads();
  for (int i = tid; i < cntb; i += 256) {
    int e = pk[i];
    int low = e & 255;
    int r = atomicAdd(&nrank[low], 1);
    adj[b * BCAP + noff[low] + r] = e >> 8;
  }
}

// ---------------- register-tiled GEMM: g[n][f] = fp16(dinv[n]*(A@W)[n][f]) ----------------
// 128 threads -> 64 nodes x 96 feats; thread: 8x6 register tile
template<int K>
__global__ __launch_bounds__(128) void k_gemm_tile(
    const float* __restrict__ A, const float* __restrict__ W,
    const float* __restrict__ dinv, __half* __restrict__ g) {
  constexpr int BM = 64, KB = 32;
  __shared__ float As[KB][BM + 4];
  __shared__ float Ws[KB][HID];
  int tid = threadIdx.x;       // 0..127
  int tx = tid & 15;           // f0 = tx*6
  int ty = tid >> 4;           // 0..7 -> rows ty*8..ty*8+7
  int f0 = tx * 6;
  int nbase = blockIdx.x * BM;
  float acc[8][6] = {};

  for (int k0 = 0; k0 < K; k0 += KB) {
#pragma unroll
    for (int i = 0; i < 4; i++) {
      int l = tid + i * 128;
      int row = l >> 3;
      int col = (l & 7) * 4;
      int n = nbase + row;
      float4 a4 = make_float4(0.f, 0.f, 0.f, 0.f);
      if (n < N_NODES) a4 = *reinterpret_cast<const float4*>(A + (size_t)n * K + k0 + col);
      As[col + 0][row] = a4.x;
      As[col + 1][row] = a4.y;
      As[col + 2][row] = a4.z;
      As[col + 3][row] = a4.w;
    }
#pragma unroll
    for (int i = 0; i < 6; i++) {
      int l = tid + i * 128;
      int row = l / 24;
      int col = (l % 24) * 4;
      *reinterpret_cast<float4*>(&Ws[row][col]) =
          *reinterpret_cast<const float4*>(W + (size_t)(k0 + row) * HID + col);
    }
    __syncthreads();
#pragma unroll
    for (int k = 0; k < KB; k++) {
      float4 alo = *reinterpret_cast<const float4*>(&As[k][ty * 8]);
      float4 ahi = *reinterpret_cast<const float4*>(&As[k][ty * 8 + 4]);
      float2 w01 = *reinterpret_cast<const float2*>(&Ws[k][f0]);
      float2 w23 = *reinterpret_cast<const float2*>(&Ws[k][f0 + 2]);
      float2 w45 = *reinterpret_cast<const float2*>(&Ws[k][f0 + 4]);
      float av[8] = {alo.x, alo.y, alo.z, alo.w, ahi.x, ahi.y, ahi.z, ahi.w};
      float wv[6] = {w01.x, w01.y, w23.x, w23.y, w45.x, w45.y};
#pragma unroll
      for (int i = 0; i < 8; i++)
#pragma unroll
        for (int j = 0; j < 6; j++) acc[i][j] += av[i] * wv[j];
    }
    __syncthreads();
  }

#pragma unroll
  for (int i = 0; i < 8; i++) {
    int n = nbase + ty * 8 + i;
    if (n >= N_NODES) break;
    float d = dinv[n];
    __half2* gp = reinterpret_cast<__half2*>(g + (size_t)n * HID + f0);
#pragma unroll
    for (int j = 0; j < 3; j++)
      gp[j] = __floats2half2_rn(acc[i][2 * j] * d, acc[i][2 * j + 1] * d);
  }
}

// ---------------- fused aggregate: h = leaky(dinv*(g[n] + sum_in g[src]) + b) ----------------
// ONE vmem request per edge: fp16 row = 192B, 48 lanes x 4B dword covers it.
// Lane l holds feats (2l, 2l+1) as half2 -> unpack to 2 f32 accumulators.
__global__ __launch_bounds__(128) void k_aggregate(
    const __half* __restrict__ g, const int* __restrict__ degarr,
    const int* __restrict__ rowptr, const int* __restrict__ adj,
    const float* __restrict__ dinv, const float* __restrict__ b,
    float* __restrict__ h) {
  int n = blockIdx.x * 2 + (threadIdx.x >> 6);
  if (n >= N_NODES) return;
  int lane = threadIdx.x & 63;
  bool act = lane < 48;                    // 48 lanes x 4B = 192B row
  int deg = degarr[n];
  const int* al = adj + rowptr[n];
  int myidx = (lane < deg) ? al[lane] : 0;  // coalesced adjacency load (deg<=64 in reg)

  const char* gb = (const char*)g;
  int loff = lane * 4;
  float sx, sy;
  {
    unsigned v = act ? *(const unsigned*)(gb + (size_t)n * 192 + loff) : 0u;
    float2 t = __half22float2(*(const __half2*)&v);
    sx = t.x; sy = t.y;
  }

  int dd = deg > 64 ? 64 : deg;
  int j = 0;
  for (; j + 16 <= dd; j += 16) {
    unsigned v[16];
#pragma unroll
    for (int u = 0; u < 16; u++) {
      int idx = __shfl(myidx, j + u);
      v[u] = act ? *(const unsigned*)(gb + (size_t)idx * 192 + loff) : 0u;
    }
#pragma unroll
    for (int u = 0; u < 16; u++) {
      float2 t = __half22float2(*(const __half2*)&v[u]);
      sx += t.x; sy += t.y;
    }
  }
  if (j + 8 <= dd) {
    unsigned v[8];
#pragma unroll
    for (int u = 0; u < 8; u++) {
      int idx = __shfl(myidx, j + u);
      v[u] = act ? *(const unsigned*)(gb + (size_t)idx * 192 + loff) : 0u;
    }
#pragma unroll
    for (int u = 0; u < 8; u++) {
      float2 t = __half22float2(*(const __half2*)&v[u]);
      sx += t.x; sy += t.y;
    }
    j += 8;
  }
  if (j + 4 <= dd) {
    unsigned v[4];
#pragma unroll
    for (int u = 0; u < 4; u++) {
      int idx = __shfl(myidx, j + u);
      v[u] = act ? *(const unsigned*)(gb + (size_t)idx * 192 + loff) : 0u;
    }
#pragma unroll
    for (int u = 0; u < 4; u++) {
      float2 t = __half22float2(*(const __half2*)&v[u]);
      sx += t.x; sy += t.y;
    }
    j += 4;
  }
  for (; j < dd; j++) {
    int idx = __shfl(myidx, j);
    unsigned v = act ? *(const unsigned*)(gb + (size_t)idx * 192 + loff) : 0u;
    float2 t = __half22float2(*(const __half2*)&v);
    sx += t.x; sy += t.y;
  }
  for (; j < deg; j++) {  // deg > 64: essentially impossible, but correct
    int idx = al[j];
    unsigned v = act ? *(const unsigned*)(gb + (size_t)idx * 192 + loff) : 0u;
    float2 t = __half22float2(*(const __half2*)&v);
    sx += t.x; sy += t.y;
  }

  if (act) {
    float d = dinv[n];
    float2 bb = *reinterpret_cast<const float2*>(b + 2 * lane);
    float v0 = d * sx + bb.x;
    float v1 = d * sy + bb.y;
    v0 = v0 > 0.f ? v0 : 0.01f * v0;
    v1 = v1 > 0.f ? v1 : 0.01f * v1;
    *reinterpret_cast<float2*>(h + (size_t)n * HID + 2 * lane) = make_float2(v0, v1);
  }
}

// ---------------- final linear: out = H @ Wl + bl ----------------
__global__ __launch_bounds__(256) void k_final(
    const float* __restrict__ H, const float* __restrict__ Wl,
    const float* __restrict__ bl, float* __restrict__ out) {
  __shared__ float w[HID * NCLS];
  __shared__ float bs[NCLS];
  int tid = threadIdx.x;
  for (int i = tid; i < HID * NCLS; i += 256) w[i] = Wl[i];
  if (tid < NCLS) bs[tid] = bl[tid];
  __syncthreads();
  int idx = blockIdx.x * 256 + tid;
  if (idx >= N_NODES * NCLS) return;
  int n = idx / NCLS;
  int c = idx - n * NCLS;
  const float* a = H + (size_t)n * HID;
  float s = bs[c];
#pragma unroll
  for (int k = 0; k < HID; k++) s += a[k] * w[k * NCLS + c];
  out[idx] = s;
}

extern "C" void kernel_launch(void* const* d_in, const int* in_sizes, int n_in,
                              void* d_out, int out_size, void* d_ws, size_t ws_size,
                              hipStream_t stream) {
  const float* x  = (const float*)d_in[0];
  const int* ei   = (const int*)d_in[1];
  const int* src  = ei;             // edge_index[0]
  const int* tgt  = ei + N_EDGES;   // edge_index[1]
  const float* W1 = (const float*)d_in[2];
  const float* b1 = (const float*)d_in[3];
  const float* W2 = (const float*)d_in[4];
  const float* b2 = (const float*)d_in[5];
  const float* W3 = (const float*)d_in[6];
  const float* b3 = (const float*)d_in[7];
  const float* Wl = (const float*)d_in[8];
  const float* bl = (const float*)d_in[9];
  float* out = (float*)d_out;

  // workspace layout
  float*  dinv   = (float*)d_ws;                            // N
  __half* gh     = (__half*)(dinv + N_NODES);               // N*96 fp16 (gather payload)
  float*  bufB   = (float*)(gh + (size_t)N_NODES * HID);    // N*96 f32 (h)
  int*    degarr = (int*)(bufB + (size_t)N_NODES * HID);    // N
  int*    rowptr = degarr + N_NODES;                        // N
  int*    cursor = rowptr + N_NODES;                        // NBUCK*CPAD
  int*    packed = cursor + NBUCK * CPAD;                   // NBUCK*BCAP
  int*    adj    = packed + NBUCK * BCAP;                   // NBUCK*BCAP

  // ---- CSR build via 2-level counting sort ----
  hipMemsetAsync(cursor, 0, NBUCK * CPAD * sizeof(int), stream);
  k_bin<<<(N_EDGES + 4095) / 4096, 1024, 0, stream>>>(src, tgt, cursor, packed);
  k_build<<<NBUCK, 256, 0, stream>>>(cursor, packed, adj, degarr, rowptr, dinv);

  const int ggrid = (N_NODES + 63) / 64;
  const int agrid = (N_NODES + 1) / 2;

  // ---- layer 1 ----
  k_gemm_tile<IN_F><<<ggrid, 128, 0, stream>>>(x, W1, dinv, gh);
  k_aggregate<<<agrid, 128, 0, stream>>>(gh, degarr, rowptr, adj, dinv, b1, bufB);
  // ---- layer 2 ----
  k_gemm_tile<HID><<<ggrid, 128, 0, stream>>>(bufB, W2, dinv, gh);
  k_aggregate<<<agrid, 128, 0, stream>>>(gh, degarr, rowptr, adj, dinv, b2, bufB);
  // ---- layer 3 ----
  k_gemm_tile<HID><<<ggrid, 128, 0, stream>>>(bufB, W3, dinv, gh);
  k_aggregate<<<agrid, 128, 0, stream>>>(gh, degarr, rowptr, adj, dinv, b3, bufB);

  // ---- classifier ----
  k_final<<<(N_NODES * NCLS + 255) / 256, 256, 0, stream>>>(bufB, Wl, bl, out);
}